// Round 7
// baseline (510.098 us; speedup 1.0000x reference)
//
#include <hip/hip_runtime.h>
#include <hip/hip_bf16.h>

#define N_NODES 8192
#define IN_F 512
#define OUT_F 128
#define KP 8                      // k-partitions
#define KT_PER 32                 // k-tiles (32 cols) per partition
#define NWORDS (N_NODES / 32)     // packed words per adj row = 256
#define LOG2E 1.4426950408889634f

typedef unsigned short u16;
typedef unsigned int u32;
typedef short s16x8 __attribute__((ext_vector_type(8)));
typedef float f32x4 __attribute__((ext_vector_type(4)));
typedef u32 u32x4 __attribute__((ext_vector_type(4)));

__device__ __forceinline__ u16 f2bf(float f) {
    union { float f; unsigned u; } x; x.f = f;
    unsigned r = x.u + 0x7FFFu + ((x.u >> 16) & 1u);
    return (u16)(r >> 16);
}

// HW pack: v_cvt_pk_bf16_f32 (rne) -> u32 (lo=a, hi=b)
__device__ __forceinline__ u32 packbf2(float a, float b) {
    __hip_bfloat162 h = __float22bfloat162_rn(make_float2(a, b));
    u32 u; __builtin_memcpy(&u, &h, 4);
    return u;
}

// edge weight: exp(sigmoid(alpha)) or 0 if masked
__device__ __forceinline__ float edge_p(float wh1, float w2, int keep) {
    float alpha = wh1 + w2;
    float e = exp2f(-LOG2E * alpha);
    float s = __builtin_amdgcn_rcpf(1.0f + e);
    float p = exp2f(LOG2E * s);
    return keep ? p : 0.0f;
}

// ---- K0 "prep": three independent jobs fused into one dispatch.
//  blocks [0, 8192):    pack adj int32 -> 1-bit bitmap (256 MB -> 8 MB)
//  blocks [8192, 8448): repack W fp32 -> bf16 MFMA B-fragment layout
//  blocks [8448, 8450): Wa1 = W@a1, Wa2 = W@a2
__global__ __launch_bounds__(256)
void prep(const int* __restrict__ adj, const float* __restrict__ W,
          const float* __restrict__ a1, const float* __restrict__ a2,
          u32* __restrict__ Pk, u16* __restrict__ W_frag,
          float* __restrict__ Wa1, float* __restrict__ Wa2) {
    int b = blockIdx.x;
    int tid = threadIdx.x;
    if (b < 8192) {
        int gid = b * 256 + tid;                  // word index, 2M total
        const int* src = adj + (size_t)gid * 32;
        u32 bits = 0;
        #pragma unroll
        for (int t = 0; t < 8; t++) {
            int4 v = *(const int4*)(src + t * 4);
            bits |= (u32)(v.x > 0) << (t * 4 + 0);
            bits |= (u32)(v.y > 0) << (t * 4 + 1);
            bits |= (u32)(v.z > 0) << (t * 4 + 2);
            bits |= (u32)(v.w > 0) << (t * 4 + 3);
        }
        Pk[gid] = bits;
    } else if (b < 8448) {
        int t2 = (b - 8192) * 256 + tid;          // 0..65535
        int j = t2 & 7;
        int lane = (t2 >> 3) & 63;
        int nt = (t2 >> 9) & 7;
        int kt = t2 >> 12;
        int k = kt * 32 + (lane >> 4) * 8 + j;
        int n = nt * 16 + (lane & 15);
        W_frag[t2] = f2bf(W[k * OUT_F + n]);
    } else {
        int k = (b - 8448) * 256 + tid;           // 0..511
        float s1 = 0.f, s2 = 0.f;
        #pragma unroll 8
        for (int n = 0; n < OUT_F; n++) {
            float w = W[k * OUT_F + n];
            s1 += w * a1[n];
            s2 += w * a2[n];
        }
        Wa1[k] = s1; Wa2[k] = s2;
    }
}

// ---- K1 hybrid: blocks [0,256): h = X@W with W-fragments RESIDENT in VGPRs
// and X staged as pre-packed bf16 A-fragments in a 16 KB LDS double buffer
// (compute phase has ZERO vmem). blocks [256,272): Wh1/Wh2 = X@Wa (f32,
// pure-streaming dot, one thread per row).
__global__ __launch_bounds__(512, 2)
void gemm_h(const float* __restrict__ X, const u16* __restrict__ W_frag,
            const float* __restrict__ Wa1, const float* __restrict__ Wa2,
            float* __restrict__ Wh1, float* __restrict__ Wh2,
            u16* __restrict__ h_frag) {
    int tid = threadIdx.x;
    if (blockIdx.x >= 256) {
        int r = (blockIdx.x - 256) * 512 + tid;   // 0..8191
        const float4* xr = (const float4*)(X + (size_t)r * IN_F);
        const float4* a4 = (const float4*)Wa1;
        const float4* b4 = (const float4*)Wa2;
        float s1 = 0.f, s2 = 0.f;
        #pragma unroll 4
        for (int i = 0; i < 128; i++) {
            float4 x = xr[i], a = a4[i], bb = b4[i];
            s1 += x.x*a.x + x.y*a.y + x.z*a.z + x.w*a.w;
            s2 += x.x*bb.x + x.y*bb.y + x.z*bb.z + x.w*bb.w;
        }
        Wh1[r] = s1; Wh2[r] = s2;
        return;
    }

    __shared__ u32x4 AXL[2][512];   // [buf][tile*256 + ktl*64 + lane], 16 KB
    int wave = tid >> 6;            // = nt
    int lane = tid & 63;
    int quad = lane >> 4;
    int lid = lane & 15;
    int rbase = blockIdx.x * 32;    // 32 rows/block (two 16-row tiles)
    const s16x8* Wf = (const s16x8*)W_frag;

    // resident B-fragments: 16 x s16x8 = 64 VGPR, loaded once
    s16x8 Wr[16];
    #pragma unroll
    for (int kt = 0; kt < 16; kt++) Wr[kt] = Wf[(kt * 8 + wave) * 64 + lane];

    // stage mapping: thread t <-> fragment (tile = t>>8, ktl = (t>>6)&3, lane)
    int s_tile = tid >> 8, s_ktl = (tid >> 6) & 3, s_lane = tid & 63;
    int s_row = rbase + s_tile * 16 + (s_lane & 15);
    const float* s_base = X + (size_t)s_row * IN_F + (s_lane >> 4) * 8;

    f32x4 acc0 = {}, acc1 = {};
    // prologue: chunk 0 loads
    float4 x0 = *(const float4*)(s_base + s_ktl * 32);
    float4 x1 = *(const float4*)(s_base + s_ktl * 32 + 4);

    #pragma unroll      // FULL unroll: keeps Wr[] indices compile-time static
    for (int c = 0; c < 4; c++) {
        asm volatile("s_waitcnt vmcnt(0)" ::: "memory");
        u32x4 v;
        v.x = packbf2(x0.x, x0.y); v.y = packbf2(x0.z, x0.w);
        v.z = packbf2(x1.x, x1.y); v.w = packbf2(x1.z, x1.w);
        AXL[c & 1][tid] = v;
        int cn = (c + 1 < 4) ? c + 1 : c;         // clamp (no OOB)
        x0 = *(const float4*)(s_base + (cn * 4 + s_ktl) * 32);
        x1 = *(const float4*)(s_base + (cn * 4 + s_ktl) * 32 + 4);
        asm volatile("s_waitcnt lgkmcnt(0)" ::: "memory");
        __builtin_amdgcn_s_barrier();
        __builtin_amdgcn_sched_barrier(0);
        const s16x8* AB = (const s16x8*)&AXL[c & 1][0];
        #pragma unroll
        for (int ktl = 0; ktl < 4; ktl++) {
            s16x8 a0 = AB[ktl * 64 + lane];
            s16x8 a1 = AB[256 + ktl * 64 + lane];
            acc0 = __builtin_amdgcn_mfma_f32_16x16x32_bf16(a0, Wr[c * 4 + ktl], acc0, 0, 0, 0);
            acc1 = __builtin_amdgcn_mfma_f32_16x16x32_bf16(a1, Wr[c * 4 + ktl], acc1, 0, 0, 0);
        }
        // single barrier per chunk is sufficient: write(c+1) targets the
        // other buffer; reuse of this buffer (write at c+2) is separated
        // from compute(c) by barrier(c+1).
    }

    #pragma unroll
    for (int reg = 0; reg < 4; reg++) {
        int row = rbase + quad * 4 + reg;                 // tile 0
        int ktile = row >> 5, kl = row & 31;
        int lane2 = (kl >> 3) * 16 + lid, j2 = kl & 7;
        h_frag[(size_t)((ktile * 8 + wave) * 64 + lane2) * 8 + j2] = f2bf(acc0[reg]);
        int row1 = row + 16;                              // tile 1
        int ktile1 = row1 >> 5, kl1 = row1 & 31;
        int lane21 = (kl1 >> 3) * 16 + lid, j21 = kl1 & 7;
        h_frag[(size_t)((ktile1 * 8 + wave) * 64 + lane21) * 8 + j21] = f2bf(acc1[reg]);
    }
}

// ---- K2: attention with a vmem-FREE compute loop. 64 rtiles x KP(8) = 512
// blocks x 256 thr (4 waves; 2 blocks/CU at 68 KB LDS). Block owns 128 rows
// (wave: 32) and kt-range [kh*32, kh*32+32), processed as 8 chunks of 4 kt.
// Per chunk: {vmcnt(0) for staged regs; ds_write h_frag chunk to LDS buf;
// issue next chunk's global loads (h_frag + Pk); lgkm-only drain; raw
// s_barrier; compute 4 kt from LDS + Pk regs}. The prefetched loads stay in
// flight across the barrier and the whole compute phase.
__global__ __launch_bounds__(256, 2)
void attn_kernel(const u32* __restrict__ Pk, const float* __restrict__ Wh1,
                 const float* __restrict__ Wh2, const u16* __restrict__ h_frag,
                 float* __restrict__ out_part, float* __restrict__ sum_part) {
    __shared__ u32x4 HfL[2][2048];   // [buf][ktl*512 + nt*64 + lane], 64 KB
    __shared__ float Wh2L[1024];     // this partition's Wh2 slice, 4 KB

    int tid = threadIdx.x;
    int wave = tid >> 6;
    int lane = tid & 63;
    int quad = lane >> 4;
    int lid = lane & 15;
    int rtile = blockIdx.x >> 3;
    int kh = blockIdx.x & (KP - 1);
    int rbase = rtile * 128 + wave * 32;
    int r0 = rbase + lid, r1 = r0 + 16;

    float wh10 = Wh1[r0], wh11 = Wh1[r1];
    f32x4 acc0[8] = {}, acc1[8] = {};
    float ps0 = 0.f, ps1 = 0.f;
    const u32x4* Hg = (const u32x4*)h_frag + (size_t)(kh * KT_PER) * 512;
    const u32* prow0 = Pk + (size_t)r0 * NWORDS + kh * KT_PER;
    const u32* prow1 = Pk + (size_t)r1 * NWORDS + kh * KT_PER;

    // prologue: Wh2 slice -> LDS; chunk 0 frags + Pk words -> regs
    ((float4*)Wh2L)[tid] = ((const float4*)Wh2)[kh * 256 + tid];
    u32x4 st[8];
    #pragma unroll
    for (int i = 0; i < 8; i++) st[i] = Hg[i * 256 + tid];
    u32x4 P0r = *(const u32x4*)(prow0);
    u32x4 P1r = *(const u32x4*)(prow1);

    auto step = [&](int ktg, u32 pw0, u32 pw1, const s16x8* HB) {
        int ktl = ktg & 3;
        float4 w20 = *(const float4*)&Wh2L[ktg * 32 + quad * 8];
        float4 w21 = *(const float4*)&Wh2L[ktg * 32 + quad * 8 + 4];
        u32 w0 = pw0 >> (quad * 8);
        u32 w1 = pw1 >> (quad * 8);

        float e0 = edge_p(wh10, w20.x, (w0 >> 0) & 1);
        float e1 = edge_p(wh10, w20.y, (w0 >> 1) & 1);
        float e2 = edge_p(wh10, w20.z, (w0 >> 2) & 1);
        float e3 = edge_p(wh10, w20.w, (w0 >> 3) & 1);
        float e4 = edge_p(wh10, w21.x, (w0 >> 4) & 1);
        float e5 = edge_p(wh10, w21.y, (w0 >> 5) & 1);
        float e6 = edge_p(wh10, w21.z, (w0 >> 6) & 1);
        float e7 = edge_p(wh10, w21.w, (w0 >> 7) & 1);
        ps0 += ((e0 + e1) + (e2 + e3)) + ((e4 + e5) + (e6 + e7));
        u32x4 uv0;
        uv0.x = packbf2(e0, e1); uv0.y = packbf2(e2, e3);
        uv0.z = packbf2(e4, e5); uv0.w = packbf2(e6, e7);

        float f0 = edge_p(wh11, w20.x, (w1 >> 0) & 1);
        float f1 = edge_p(wh11, w20.y, (w1 >> 1) & 1);
        float f2 = edge_p(wh11, w20.z, (w1 >> 2) & 1);
        float f3 = edge_p(wh11, w20.w, (w1 >> 3) & 1);
        float f4 = edge_p(wh11, w21.x, (w1 >> 4) & 1);
        float f5 = edge_p(wh11, w21.y, (w1 >> 5) & 1);
        float f6 = edge_p(wh11, w21.z, (w1 >> 6) & 1);
        float f7 = edge_p(wh11, w21.w, (w1 >> 7) & 1);
        ps1 += ((f0 + f1) + (f2 + f3)) + ((f4 + f5) + (f6 + f7));
        u32x4 uv1;
        uv1.x = packbf2(f0, f1); uv1.y = packbf2(f2, f3);
        uv1.z = packbf2(f4, f5); uv1.w = packbf2(f6, f7);

        s16x8 af0 = __builtin_bit_cast(s16x8, uv0);
        s16x8 af1 = __builtin_bit_cast(s16x8, uv1);

        #pragma unroll
        for (int nt = 0; nt < 8; nt++) {
            s16x8 b = HB[(ktl * 8 + nt) * 64 + lane];
            acc0[nt] = __builtin_amdgcn_mfma_f32_16x16x32_bf16(af0, b, acc0[nt], 0, 0, 0);
            acc1[nt] = __builtin_amdgcn_mfma_f32_16x16x32_bf16(af1, b, acc1[nt], 0, 0, 0);
        }
    };

    #pragma unroll 1
    for (int c = 0; c < 8; c++) {
        asm volatile("s_waitcnt vmcnt(0)" ::: "memory");
        u32x4* dst = &HfL[c & 1][0];
        #pragma unroll
        for (int i = 0; i < 8; i++) dst[i * 256 + tid] = st[i];
        u32x4 cP0 = P0r, cP1 = P1r;
        int cn = (c + 1 < 8) ? c + 1 : c;         // clamp (no OOB)
        const u32x4* src = Hg + cn * 2048;
        #pragma unroll
        for (int i = 0; i < 8; i++) st[i] = src[i * 256 + tid];
        P0r = *(const u32x4*)(prow0 + cn * 4);
        P1r = *(const u32x4*)(prow1 + cn * 4);
        asm volatile("s_waitcnt lgkmcnt(0)" ::: "memory");
        __builtin_amdgcn_s_barrier();
        __builtin_amdgcn_sched_barrier(0);
        const s16x8* HB = (const s16x8*)&HfL[c & 1][0];
        step(c * 4 + 0, cP0.x, cP1.x, HB);
        step(c * 4 + 1, cP0.y, cP1.y, HB);
        step(c * 4 + 2, cP0.z, cP1.z, HB);
        step(c * 4 + 3, cP0.w, cP1.w, HB);
        // single barrier per chunk: writes(c+1) go to the other buffer;
        // this buffer's reuse (write at c+2) is fenced by barrier(c+1).
    }

    ps0 += __shfl_xor(ps0, 16, 64); ps0 += __shfl_xor(ps0, 32, 64);
    ps1 += __shfl_xor(ps1, 16, 64); ps1 += __shfl_xor(ps1, 32, 64);
    if (quad == 0) {
        sum_part[(size_t)kh * N_NODES + r0] = ps0;
        sum_part[(size_t)kh * N_NODES + r1] = ps1;
    }

    #pragma unroll
    for (int nt = 0; nt < 8; nt++) {
        #pragma unroll
        for (int reg = 0; reg < 4; reg++) {
            int row0 = rbase + quad * 4 + reg;
            int col = nt * 16 + lid;
            out_part[((size_t)kh * N_NODES + row0) * OUT_F + col] = acc0[nt][reg];
            out_part[((size_t)kh * N_NODES + row0 + 16) * OUT_F + col] = acc1[nt][reg];
        }
    }
}

// ---- K3: out = (sum_k part_k) / (sum_k rowsum_k)
__global__ void finalize(const float* __restrict__ out_part,
                         const float* __restrict__ sum_part,
                         float* __restrict__ out) {
    int gid = blockIdx.x * 256 + threadIdx.x;
    int i = gid >> 7;
    float s = 0.f, v = 0.f;
    for (int kh = 0; kh < KP; kh++) {
        s += sum_part[(size_t)kh * N_NODES + i];
        v += out_part[(size_t)kh * N_NODES * OUT_F + gid];
    }
    out[gid] = v / s;
}

extern "C" void kernel_launch(void* const* d_in, const int* in_sizes, int n_in,
                              void* d_out, int out_size, void* d_ws, size_t ws_size,
                              hipStream_t stream) {
    const float* X   = (const float*)d_in[0];
    const int*   adj = (const int*)d_in[1];
    const float* W   = (const float*)d_in[2];
    const float* a1  = (const float*)d_in[3];
    const float* a2  = (const float*)d_in[4];

    char* ws = (char*)d_ws;
    float* Wh1 = (float*)(ws);                         // 32 KB
    float* Wh2 = (float*)(ws + (32 << 10));            // 32 KB
    float* Wa1 = (float*)(ws + (64 << 10));            // 2 KB
    float* Wa2 = (float*)(ws + (66 << 10));            // 2 KB
    u16* W_frag = (u16*)(ws + (128 << 10));            // 128 KB
    u16* h_frag = (u16*)(ws + (256 << 10));            // 2 MB (ends 2.25 MB)
    u32* Pk     = (u32*)(ws + ((size_t)4 << 20));      // 8 MB packed adj
    float* out_part = (float*)(ws + ((size_t)16 << 20));   // KP*4 MB = 32 MB
    float* sum_part = (float*)(ws + ((size_t)48 << 20));   // KP*32 KB
    float* out = (float*)d_out;

    hipLaunchKernelGGL(prep, dim3(8450), dim3(256), 0, stream,
                       adj, W, a1, a2, Pk, W_frag, Wa1, Wa2);
    hipLaunchKernelGGL(gemm_h, dim3(272), dim3(512), 0, stream,
                       X, W_frag, Wa1, Wa2, Wh1, Wh2, h_frag);
    hipLaunchKernelGGL(attn_kernel, dim3(64 * KP), dim3(256), 0, stream,
                       Pk, Wh1, Wh2, h_frag, out_part, sum_part);
    hipLaunchKernelGGL(finalize, dim3((N_NODES * OUT_F) / 256), dim3(256), 0, stream,
                       out_part, sum_part, out);
}